// Round 2
// baseline (5642.367 us; speedup 1.0000x reference)
//
#include <hip/hip_runtime.h>
#include <hip/hip_bf16.h>
#include <cstdint>
#include <cstddef>

#define H 128

// ---------------- embedding / init ----------------

__global__ __launch_bounds__(256) void atom_encode_k(const int* __restrict__ nf,
    const float* __restrict__ emb, float* __restrict__ x, float* __restrict__ abuf, int N) {
  long long t = (long long)blockIdx.x * 256 + threadIdx.x;
  if (t >= (long long)N * H) return;
  int n = (int)(t >> 7), h = (int)(t & 127);
  const int* row = nf + (size_t)n * 9;
  float s = 0.f;
#pragma unroll
  for (int f = 0; f < 9; ++f) {
    s += emb[((size_t)f * 100 + row[f]) * H + h];
  }
  x[t] = s;
  abuf[t] = s;
}

__global__ __launch_bounds__(256) void rg_init_k(const int* __restrict__ feat,
    const float* __restrict__ emb, float* __restrict__ rg, int NRG) {
  long long t = (long long)blockIdx.x * 256 + threadIdx.x;
  if (t >= (long long)NRG * H) return;
  int n = (int)(t >> 7), h = (int)(t & 127);
  rg[t] = emb[(size_t)feat[n] * H + h];
}

// ---------------- edge message + scatter ----------------
// abuf pre-initialized to x; adds sum_j relu(x[src]+e) at dst -> abuf = x + agg

__global__ __launch_bounds__(256) void edge_msg_k(const int* __restrict__ ei,
    const int* __restrict__ ef, const float* __restrict__ bemb,
    const float* __restrict__ x, float* __restrict__ abuf, int E) {
  long long t = (long long)blockIdx.x * 256 + threadIdx.x;
  if (t >= (long long)E * H) return;
  int e = (int)(t >> 7), h = (int)(t & 127);
  int src = ei[e], dst = ei[(size_t)E + e];
  const int* f = ef + (size_t)e * 3;
  float v = bemb[(size_t)f[0] * H + h]
          + bemb[((size_t)100 + f[1]) * H + h]
          + bemb[((size_t)200 + f[2]) * H + h];
  float m = fmaxf(x[(size_t)src * H + h] + v, 0.f);
  atomicAdd(&abuf[(size_t)dst * H + h], m);
}

// generic row scatter-add: dst[didx[m]] += src[sidx?sidx[m]:m]
__global__ __launch_bounds__(256) void scatter_add_k(const int* __restrict__ sidx,
    const int* __restrict__ didx, const float* __restrict__ src,
    float* __restrict__ dst, int M) {
  long long t = (long long)blockIdx.x * 256 + threadIdx.x;
  if (t >= (long long)M * H) return;
  int m = (int)(t >> 7), h = (int)(t & 127);
  int sr = sidx ? sidx[m] : m;
  atomicAdd(&dst[(size_t)didx[m] * H + h], src[(size_t)sr * H + h]);
}

// ---------------- counts ----------------

__global__ __launch_bounds__(256) void count_k(const int* __restrict__ idx,
    float* __restrict__ cnt, int n) {
  int t = blockIdx.x * 256 + threadIdx.x;
  if (t < n) atomicAdd(&cnt[idx[t]], 1.0f);
}

__global__ __launch_bounds__(256) void inv_k(float* v, int n) {
  int t = blockIdx.x * 256 + threadIdx.x;
  if (t < n) v[t] = 1.0f / fmaxf(v[t], 1.0f);
}

// ---------------- batchnorm ----------------

template<int C>
__global__ __launch_bounds__(256) void bn_stats_k(const float* __restrict__ X,
    float* __restrict__ ssum, float* __restrict__ ssq, int M) {
  constexpr int TPC = 256 / C;
  int tid = threadIdx.x;
  int c = tid % C, rs = tid / C;
  float s = 0.f, q = 0.f;
  for (int r = blockIdx.x * TPC + rs; r < M; r += gridDim.x * TPC) {
    float v = X[(size_t)r * C + c];
    s += v; q = fmaf(v, v, q);
  }
  atomicAdd(&ssum[c], s);
  atomicAdd(&ssq[c], q);
}

__global__ void bn_final_k(const float* __restrict__ ssum, const float* __restrict__ ssq,
    float* __restrict__ mu, float* __restrict__ rsig, int C, float invM) {
  int c = threadIdx.x + blockIdx.x * blockDim.x;
  if (c < C) {
    float m = ssum[c] * invM;
    float v = ssq[c] * invM - m * m;
    mu[c] = m;
    rsig[c] = rsqrtf(v + 1e-5f);
  }
}

// Out = relu((X - mu) * rsig), C = 128
__global__ __launch_bounds__(256) void bn_apply_relu_k(const float* __restrict__ X,
    const float* __restrict__ mu, const float* __restrict__ rsig,
    float* __restrict__ Out, int M) {
  long long t = (long long)blockIdx.x * 256 + threadIdx.x;  // over M*32 float4s
  if (t >= (long long)M * 32) return;
  int c4 = ((int)(t & 31)) * 4;
  float4 v = ((const float4*)X)[t];
  float4 m4 = *(const float4*)&mu[c4];
  float4 r4 = *(const float4*)&rsig[c4];
  v.x = fmaxf((v.x - m4.x) * r4.x, 0.f);
  v.y = fmaxf((v.y - m4.y) * r4.y, 0.f);
  v.z = fmaxf((v.z - m4.z) * r4.z, 0.f);
  v.w = fmaxf((v.w - m4.w) * r4.w, 0.f);
  ((float4*)Out)[t] = v;
}

// ---------------- MLP stats: column sum/sumsq of A[M,128] @ W1[128,256] ----------------

__global__ __launch_bounds__(256) void mlp_stats_k(
    const float* __restrict__ A, const float* __restrict__ W1,
    float* __restrict__ ssum, float* __restrict__ ssq, int M) {
  __shared__ __align__(16) float Ash[64][128];   // 32 KB
  __shared__ float Red[2][4][256];               // 8 KB
  int tid = threadIdx.x, tc = tid & 63, tr = tid >> 6;
  int row0 = blockIdx.x * 64;
#pragma unroll
  for (int it = 0; it < 8; ++it) {
    int fidx = tid + it * 256;
    int r = fidx >> 5, c4 = (fidx & 31) << 2;
    int gr = row0 + r;
    float4 v = make_float4(0.f, 0.f, 0.f, 0.f);
    if (gr < M) v = *(const float4*)(A + (size_t)gr * 128 + c4);
    *(float4*)&Ash[r][c4] = v;
  }
  __syncthreads();
  float t[16][4];
#pragma unroll
  for (int i = 0; i < 16; ++i)
#pragma unroll
    for (int j = 0; j < 4; ++j) t[i][j] = 0.f;
  const float* Wp = W1 + tc;
  for (int kk = 0; kk < 128; kk += 4) {
    float w[4][4];
#pragma unroll
    for (int kj = 0; kj < 4; ++kj)
#pragma unroll
      for (int j = 0; j < 4; ++j)
        w[kj][j] = Wp[(size_t)(kk + kj) * 256 + j * 64];
#pragma unroll
    for (int i = 0; i < 16; ++i) {
      float4 a = *(const float4*)&Ash[tr * 16 + i][kk];
#pragma unroll
      for (int j = 0; j < 4; ++j) {
        t[i][j] = fmaf(a.x, w[0][j], t[i][j]);
        t[i][j] = fmaf(a.y, w[1][j], t[i][j]);
        t[i][j] = fmaf(a.z, w[2][j], t[i][j]);
        t[i][j] = fmaf(a.w, w[3][j], t[i][j]);
      }
    }
  }
#pragma unroll
  for (int j = 0; j < 4; ++j) {
    float s = 0.f, q = 0.f;
#pragma unroll
    for (int i = 0; i < 16; ++i) { s += t[i][j]; q = fmaf(t[i][j], t[i][j], q); }
    Red[0][tr][tc + j * 64] = s;
    Red[1][tr][tc + j * 64] = q;
  }
  __syncthreads();
  int c = tid;
  float s = Red[0][0][c] + Red[0][1][c] + Red[0][2][c] + Red[0][3][c];
  float q = Red[1][0][c] + Red[1][1][c] + Red[1][2][c] + Red[1][3][c];
  atomicAdd(&ssum[c], s);
  atomicAdd(&ssq[c], q);
}

// ---------------- fused MLP: A <- relu(BN(A@W1)) @ W2, in-place on A[M,128] ----------------

__global__ __launch_bounds__(256) void mlp_fused_k(
    float* __restrict__ A, const float* __restrict__ W1, const float* __restrict__ W2,
    const float* __restrict__ mu, const float* __restrict__ rsig, int M) {
  __shared__ __align__(16) float smem[64 * 256];  // 64 KB
  int tid = threadIdx.x, tc = tid & 63, tr = tid >> 6;
  int row0 = blockIdx.x * 64;
  // load A tile as [64][128]
#pragma unroll
  for (int it = 0; it < 8; ++it) {
    int fidx = tid + it * 256;
    int r = fidx >> 5, c4 = (fidx & 31) << 2;
    int gr = row0 + r;
    float4 v = make_float4(0.f, 0.f, 0.f, 0.f);
    if (gr < M) v = *(const float4*)(A + (size_t)gr * 128 + c4);
    *(float4*)&smem[r * 128 + c4] = v;
  }
  __syncthreads();
  // stage 1: t = A@W1 (cols tc + j*64)
  float t[16][4];
#pragma unroll
  for (int i = 0; i < 16; ++i)
#pragma unroll
    for (int j = 0; j < 4; ++j) t[i][j] = 0.f;
  const float* Wp = W1 + tc;
  for (int kk = 0; kk < 128; kk += 4) {
    float w[4][4];
#pragma unroll
    for (int kj = 0; kj < 4; ++kj)
#pragma unroll
      for (int j = 0; j < 4; ++j)
        w[kj][j] = Wp[(size_t)(kk + kj) * 256 + j * 64];
#pragma unroll
    for (int i = 0; i < 16; ++i) {
      float4 a = *(const float4*)&smem[(tr * 16 + i) * 128 + kk];
#pragma unroll
      for (int j = 0; j < 4; ++j) {
        t[i][j] = fmaf(a.x, w[0][j], t[i][j]);
        t[i][j] = fmaf(a.y, w[1][j], t[i][j]);
        t[i][j] = fmaf(a.z, w[2][j], t[i][j]);
        t[i][j] = fmaf(a.w, w[3][j], t[i][j]);
      }
    }
  }
  // BN + relu in regs
#pragma unroll
  for (int j = 0; j < 4; ++j) {
    float m = mu[tc + j * 64], rs = rsig[tc + j * 64];
#pragma unroll
    for (int i = 0; i < 16; ++i) t[i][j] = fmaxf((t[i][j] - m) * rs, 0.f);
  }
  __syncthreads();  // all reads of A-tile done; safe to overwrite smem
  // write T as [64][256]
#pragma unroll
  for (int i = 0; i < 16; ++i)
#pragma unroll
    for (int j = 0; j < 4; ++j)
      smem[(tr * 16 + i) * 256 + tc + j * 64] = t[i][j];
  __syncthreads();
  // stage 2: acc = T @ W2  (K=256, NC=128)
  float acc[16][2];
#pragma unroll
  for (int i = 0; i < 16; ++i) { acc[i][0] = 0.f; acc[i][1] = 0.f; }
  for (int kk = 0; kk < 256; kk += 4) {
    float w[4][2];
#pragma unroll
    for (int kj = 0; kj < 4; ++kj)
#pragma unroll
      for (int j = 0; j < 2; ++j)
        w[kj][j] = W2[(size_t)(kk + kj) * 128 + tc + j * 64];
#pragma unroll
    for (int i = 0; i < 16; ++i) {
      float4 a = *(const float4*)&smem[(tr * 16 + i) * 256 + kk];
#pragma unroll
      for (int j = 0; j < 2; ++j) {
        acc[i][j] = fmaf(a.x, w[0][j], acc[i][j]);
        acc[i][j] = fmaf(a.y, w[1][j], acc[i][j]);
        acc[i][j] = fmaf(a.z, w[2][j], acc[i][j]);
        acc[i][j] = fmaf(a.w, w[3][j], acc[i][j]);
      }
    }
  }
  // epilogue: in-place write h2 to A (row-block-local)
#pragma unroll
  for (int i = 0; i < 16; ++i) {
    int gr = row0 + tr * 16 + i;
    if (gr < M) {
      A[(size_t)gr * 128 + tc] = acc[i][0];
      A[(size_t)gr * 128 + tc + 64] = acc[i][1];
    }
  }
}

// ---------------- plain GEMM: Out[M,128] = op(pro(A)[M,128] @ W[128,128]) ----------------
// PRO: 0 plain, 2 A * AUX[row] (scatter-mean divide)
// EPI: 0 Out = acc; 2 Out = relu(Out + acc); 3 t = Out + relu(acc); Out = t; Out2 = t
template<int PRO, int EPI>
__global__ __launch_bounds__(256) void gemm_k(
    const float* __restrict__ A0, const float* __restrict__ AUX,
    const float* __restrict__ W, float* __restrict__ Out,
    float* __restrict__ Out2, int M) {
  __shared__ __align__(16) float Ash[64][64];
  int tid = threadIdx.x;
  int tc = tid & 63, tr = tid >> 6;
  int row0 = blockIdx.x * 64;
  float acc[16][2];
#pragma unroll
  for (int i = 0; i < 16; ++i) { acc[i][0] = 0.f; acc[i][1] = 0.f; }

  for (int k0 = 0; k0 < 128; k0 += 64) {
#pragma unroll
    for (int it = 0; it < 4; ++it) {
      int fidx = tid + it * 256;
      int r = fidx >> 4, c4 = (fidx & 15) << 2;
      int gr = row0 + r;
      float4 v = make_float4(0.f, 0.f, 0.f, 0.f);
      if (gr < M) {
        v = *(const float4*)(A0 + (size_t)gr * 128 + k0 + c4);
        if (PRO == 2) {
          float s = AUX[gr];
          v.x *= s; v.y *= s; v.z *= s; v.w *= s;
        }
      }
      *(float4*)&Ash[r][c4] = v;
    }
    __syncthreads();
    const float* Wp = W + (size_t)k0 * 128 + tc;
    for (int kk = 0; kk < 64; kk += 4) {
      float w[4][2];
#pragma unroll
      for (int kj = 0; kj < 4; ++kj)
#pragma unroll
        for (int j = 0; j < 2; ++j)
          w[kj][j] = Wp[(size_t)(kk + kj) * 128 + j * 64];
#pragma unroll
      for (int i = 0; i < 16; ++i) {
        float4 a = *(const float4*)&Ash[tr * 16 + i][kk];
#pragma unroll
        for (int j = 0; j < 2; ++j) {
          acc[i][j] = fmaf(a.x, w[0][j], acc[i][j]);
          acc[i][j] = fmaf(a.y, w[1][j], acc[i][j]);
          acc[i][j] = fmaf(a.z, w[2][j], acc[i][j]);
          acc[i][j] = fmaf(a.w, w[3][j], acc[i][j]);
        }
      }
    }
    __syncthreads();
  }
#pragma unroll
  for (int i = 0; i < 16; ++i) {
    int gr = row0 + tr * 16 + i;
    if (gr < M) {
#pragma unroll
      for (int j = 0; j < 2; ++j) {
        size_t o = (size_t)gr * 128 + tc + j * 64;
        float v = acc[i][j];
        if (EPI == 0) Out[o] = v;
        else if (EPI == 2) Out[o] = fmaxf(Out[o] + v, 0.f);
        else {  // EPI == 3
          float tt = Out[o] + fmaxf(v, 0.f);
          Out[o] = tt;
          Out2[o] = tt;
        }
      }
    }
  }
}

// ---------------- host ----------------

static inline int cdivll(long long a, long long b) { return (int)((a + b - 1) / b); }

extern "C" void kernel_launch(void* const* d_in, const int* in_sizes, int n_in,
                              void* d_out, int out_size, void* d_ws, size_t ws_size,
                              hipStream_t stream) {
  const int* node_feat  = (const int*)d_in[0];
  const int* edge_index = (const int*)d_in[1];
  const int* edge_feat  = (const int*)d_in[2];
  const int* batch      = (const int*)d_in[3];
  const int* map_row    = (const int*)d_in[4];
  const int* map_col    = (const int*)d_in[5];
  const int* rg_ei      = (const int*)d_in[6];
  const int* rg_feat    = (const int*)d_in[7];
  const int* tree_batch = (const int*)d_in[8];
  const float* atom_emb   = (const float*)d_in[10];
  const float* bond_emb   = (const float*)d_in[11];
  const float* rg_emb     = (const float*)d_in[12];
  const float* atom_W1    = (const float*)d_in[13];
  const float* atom_W2    = (const float*)d_in[14];
  const float* rg_W1      = (const float*)d_in[15];
  const float* rg_W2      = (const float*)d_in[16];
  const float* raw2rg_W   = (const float*)d_in[17];
  const float* rg2raw_W   = (const float*)d_in[18];
  const float* atom_lin_W = (const float*)d_in[19];
  const float* rg_lin_W   = (const float*)d_in[20];
  const float* lin_W      = (const float*)d_in[21];

  const int N   = in_sizes[0] / 9;
  const int E   = in_sizes[1] / 2;
  const int M   = in_sizes[4];
  const int NRG = in_sizes[7];
  const int ERG = in_sizes[6] / 2;
  const int G   = out_size / H;
  if (N <= 0 || G <= 0) return;

  const size_t NH = (size_t)N * H, RH = (size_t)NRG * H, GH = (size_t)G * H;
  const size_t need = 2 * NH + RH + (size_t)NRG + (size_t)N + 2 * (size_t)G + 1024;
  if (ws_size < need * sizeof(float)) return;  // diagnostic: fail cleanly, don't fault

  float* ws = (float*)d_ws;
  size_t off = 0;
  auto alloc = [&](size_t n) { float* p = ws + off; off += n; return p; };
  float* x    = alloc(NH);
  float* abuf = alloc(NH);
  float* rg   = alloc(RH);
  float* cnt_col   = alloc((size_t)NRG);
  float* cnt_row   = alloc((size_t)N);
  float* cnt_batch = alloc((size_t)G);
  float* cnt_tree  = alloc((size_t)G);
  float* ssum = alloc(256);
  float* ssq  = alloc(256);
  float* mu   = alloc(256);
  float* rsig = alloc(256);

  // ---- counts ----
  hipMemsetAsync(cnt_col, 0, (size_t)(NRG + N + 2 * G) * 4, stream);
  count_k<<<cdivll(M, 256), 256, 0, stream>>>(map_col, cnt_col, M);
  count_k<<<cdivll(M, 256), 256, 0, stream>>>(map_row, cnt_row, M);
  count_k<<<cdivll(N, 256), 256, 0, stream>>>(batch, cnt_batch, N);
  count_k<<<cdivll(NRG, 256), 256, 0, stream>>>(tree_batch, cnt_tree, NRG);
  inv_k<<<cdivll(NRG + N + 2 * G, 256), 256, 0, stream>>>(cnt_col, NRG + N + 2 * G);

  // ---- encoders (abuf := x) ----
  atom_encode_k<<<cdivll(NH, 256), 256, 0, stream>>>(node_feat, atom_emb, x, abuf, N);
  rg_init_k<<<cdivll(RH, 256), 256, 0, stream>>>(rg_feat, rg_emb, rg, NRG);

  for (int i = 0; i < 3; ++i) {
    // --- GINE: abuf += scatter relu(x[src]+e) => abuf = x + agg ---
    edge_msg_k<<<cdivll((long long)E * H, 256), 256, 0, stream>>>(
        edge_index, edge_feat, bond_emb + (size_t)i * 3 * 100 * H, x, abuf, E);
    // --- atom MLP: stats(BN1) -> fused -> stats(BN2) -> apply -> x ---
    hipMemsetAsync(ssum, 0, 512 * 4, stream);
    mlp_stats_k<<<cdivll(N, 64), 256, 0, stream>>>(abuf, atom_W1 + (size_t)i * H * 2 * H, ssum, ssq, N);
    bn_final_k<<<1, 256, 0, stream>>>(ssum, ssq, mu, rsig, 256, 1.0f / N);
    mlp_fused_k<<<cdivll(N, 64), 256, 0, stream>>>(abuf, atom_W1 + (size_t)i * H * 2 * H,
        atom_W2 + (size_t)i * 2 * H * H, mu, rsig, N);
    hipMemsetAsync(ssum, 0, 512 * 4, stream);
    bn_stats_k<128><<<512, 256, 0, stream>>>(abuf, ssum, ssq, N);
    bn_final_k<<<1, 256, 0, stream>>>(ssum, ssq, mu, rsig, 128, 1.0f / N);
    bn_apply_relu_k<<<cdivll((long long)N * 32, 256), 256, 0, stream>>>(abuf, mu, rsig, x, N);

    // --- raw -> rg: sm_rg (abuf[0:RH]) ---
    hipMemsetAsync(abuf, 0, RH * 4, stream);
    scatter_add_k<<<cdivll((long long)M * H, 256), 256, 0, stream>>>(map_row, map_col, x, abuf, M);
    // rg = rg + relu(sm/cnt @ W); arg(abuf) := rg
    gemm_k<2, 3><<<cdivll(NRG, 64), 256, 0, stream>>>(abuf, cnt_col,
        raw2rg_W + (size_t)i * H * H, rg, abuf, NRG);

    // --- rg GIN: arg += scatter rg[rsrc] at rdst ---
    scatter_add_k<<<cdivll((long long)ERG * H, 256), 256, 0, stream>>>(rg_ei, rg_ei + ERG, rg, abuf, ERG);
    hipMemsetAsync(ssum, 0, 512 * 4, stream);
    mlp_stats_k<<<cdivll(NRG, 64), 256, 0, stream>>>(abuf, rg_W1 + (size_t)i * H * 2 * H, ssum, ssq, NRG);
    bn_final_k<<<1, 256, 0, stream>>>(ssum, ssq, mu, rsig, 256, 1.0f / NRG);
    mlp_fused_k<<<cdivll(NRG, 64), 256, 0, stream>>>(abuf, rg_W1 + (size_t)i * H * 2 * H,
        rg_W2 + (size_t)i * 2 * H * H, mu, rsig, NRG);
    hipMemsetAsync(ssum, 0, 512 * 4, stream);
    bn_stats_k<128><<<512, 256, 0, stream>>>(abuf, ssum, ssq, NRG);
    bn_final_k<<<1, 256, 0, stream>>>(ssum, ssq, mu, rsig, 128, 1.0f / NRG);
    bn_apply_relu_k<<<cdivll((long long)NRG * 32, 256), 256, 0, stream>>>(abuf, mu, rsig, rg, NRG);

    // --- rg -> raw: sm_raw (abuf[0:NH]) ---
    hipMemsetAsync(abuf, 0, NH * 4, stream);
    scatter_add_k<<<cdivll((long long)M * H, 256), 256, 0, stream>>>(map_col, map_row, rg, abuf, M);
    // x = x + relu(sm/cnt @ W); abuf := x  (ready for next layer's edge_msg)
    gemm_k<2, 3><<<cdivll(N, 64), 256, 0, stream>>>(abuf, cnt_row,
        rg2raw_W + (size_t)i * H * H, x, abuf, N);
  }

  // ---- readout ----
  float* xg  = abuf;           // [G,H]
  float* rgg = abuf + GH;      // [G,H]
  float* P   = abuf + 2 * GH;  // [G,H]
  hipMemsetAsync(abuf, 0, 2 * GH * 4, stream);
  scatter_add_k<<<cdivll(NH, 256), 256, 0, stream>>>(nullptr, batch, x, xg, N);
  scatter_add_k<<<cdivll(RH, 256), 256, 0, stream>>>(nullptr, tree_batch, rg, rgg, NRG);
  gemm_k<2, 0><<<cdivll(G, 64), 256, 0, stream>>>(xg, cnt_batch, atom_lin_W, P, nullptr, G);
  gemm_k<2, 2><<<cdivll(G, 64), 256, 0, stream>>>(rgg, cnt_tree, rg_lin_W, P, nullptr, G);
  gemm_k<0, 0><<<cdivll(G, 64), 256, 0, stream>>>(P, nullptr, lin_W, (float*)d_out, nullptr, G);
}